// Round 18
// baseline (626.847 us; speedup 1.0000x reference)
//
#include <hip/hip_runtime.h>
#include <cstdint>

// CausalSelfAttention fused pipeline, all-bf16 MFMA path.
// R18 = R17 (swapped-QK^T body, 4-batch-wave grid, relt L1-sharing) plus:
//  (1) 2-deep register pipeline across k-tiles: tile kt+1's K/V/rel loads issue
//      BEFORE tile kt's compute (named A/B buffers, unrolled-2 loop, no runtime
//      indexing) — FIFO vmcnt keeps them in flight across kt's waits, hiding the
//      ~250cy L2 latency that was exposed at every tile top.
//  (2) exp2-domain softmax: log2(e) folded into Q-scale + relt -> exp2f (saves
//      a v_mul per score), fma for the non-table rel path.
// ws layout (ushort): Qf[8.39M] Kf[8.39M] Vf[8.39M] XbAO[8.39M] WtQ[786K] WtO[262K] [relt 33.55M]

#define DEVI __device__ __forceinline__

typedef __bf16 bf8 __attribute__((ext_vector_type(8)));
typedef float f4 __attribute__((ext_vector_type(4)));
typedef unsigned short us8 __attribute__((ext_vector_type(8)));
typedef unsigned short us4 __attribute__((ext_vector_type(4)));

typedef const unsigned int __attribute__((address_space(1))) gu32;
typedef unsigned int __attribute__((address_space(3))) lu32;

#define L2E 1.44269504088896f

DEVI unsigned short f2bf(float f) {  // RNE f32->bf16 (prep/GEMM epilogues)
  unsigned u = __builtin_bit_cast(unsigned, f);
  u += 0x7fffu + ((u >> 16) & 1u);
  return (unsigned short)(u >> 16);
}

DEVI unsigned short cbf(float f) {   // compiler-lowered cast (v_cvt_pk_bf16_f32 pairs)
  return __builtin_bit_cast(unsigned short, (__bf16)f);
}

DEVI void gl_lds16(const void* g, void* l) {
  __builtin_amdgcn_global_load_lds((gu32*)g, (lu32*)l, 16, 0, 0);
}

// ---------------- prep: x (f32 [16384][512]) -> bf16, chunk-swizzled ----------------
__global__ __launch_bounds__(256) void k_convert_x(const float* __restrict__ x,
                                                   unsigned short* __restrict__ xb) {
  int c = blockIdx.x * 256 + threadIdx.x;   // 1,048,576 chunks
  int row = c >> 6, cl = c & 63;
  const float* s = x + ((size_t)row << 9) + (cl << 3);
  float4 a = *(const float4*)s;
  float4 b = *(const float4*)(s + 4);
  us8 o;
  o[0]=f2bf(a.x); o[1]=f2bf(a.y); o[2]=f2bf(a.z); o[3]=f2bf(a.w);
  o[4]=f2bf(b.x); o[5]=f2bf(b.y); o[6]=f2bf(b.z); o[7]=f2bf(b.w);
  int p = (cl & ~7) | ((cl & 7) ^ (row & 7));
  *(us8*)(xb + ((size_t)row << 9) + (p << 3)) = o;
}

// ------------- prep: W [512][N] f32 -> Wt [N][512] bf16, chunk-swizzled -------------
__global__ __launch_bounds__(256) void k_transpose_w(const float* __restrict__ W,
                                                     unsigned short* __restrict__ Wt, int N) {
  __shared__ float t[32][33];
  int k0 = blockIdx.x * 32, n0 = blockIdx.y * 32;
  int tx = threadIdx.x & 31, ty = threadIdx.x >> 5;
#pragma unroll
  for (int r = 0; r < 4; ++r)
    t[ty + r * 8][tx] = W[(size_t)(k0 + ty + r * 8) * N + n0 + tx];
  __syncthreads();
#pragma unroll
  for (int r = 0; r < 4; ++r) {
    int n = n0 + ty + r * 8, k = k0 + tx;
    int k2 = (k & ~63) | ((((k >> 3) & 7) ^ (n & 7)) << 3) | (k & 7);
    Wt[((size_t)n << 9) + k2] = f2bf(t[tx][ty + r * 8]);
  }
}

// ---- prep: rel f32 [h][q][k] -> bf16 table, SWAPPED frag order, PRE-SCALED by log2e ----
// relt[h][q16][kt][ct][lane][j] = rel[q16*16+(lane&15)][kt*64+ct*16+4*(lane>>4)+j] * L2E
__global__ __launch_bounds__(256) void k_relconv(const float* __restrict__ rel,
                                                 unsigned short* __restrict__ relt) {
  int t = blockIdx.x * 256 + threadIdx.x;   // 8.39M threads
  int lane = t & 63, ct = (t >> 6) & 3, kt = (t >> 8) & 31, q16 = (t >> 13) & 127, h = t >> 20;
  if (kt > (q16 >> 2)) return;              // above-diagonal tiles never read
  int row = (q16 << 4) + (lane & 15);
  int col = (kt << 6) + (ct << 4) + ((lane >> 4) << 2);
  float4 v = *(const float4*)(rel + ((size_t)h << 22) + ((size_t)row << 11) + col);
  us4 o;
  o[0] = f2bf(v.x * L2E); o[1] = f2bf(v.y * L2E);
  o[2] = f2bf(v.z * L2E); o[3] = f2bf(v.w * L2E);
  size_t idx = ((((((size_t)h << 7) | q16) << 5) | kt) << 2 | ct) << 6 | lane;
  *(us4*)(relt + (idx << 2)) = o;
}

// ---------------- GEMM: C[M][col] = A[M][512] * Bt[col][512]^T + bias ----------------
template <int EPI>
__global__ __launch_bounds__(256, 2)
void k_gemm(const unsigned short* __restrict__ Ag, const unsigned short* __restrict__ Bg,
            const float* __restrict__ bias, float* __restrict__ Of,
            unsigned short* __restrict__ Oq, unsigned short* __restrict__ Ok,
            unsigned short* __restrict__ Ov) {
  __shared__ __align__(16) unsigned short lds[128 * 64 * 2];
  unsigned short* Al = lds;
  unsigned short* Bl = lds + 128 * 64;
  const int tid = threadIdx.x, wv = tid >> 6, lane = tid & 63, g = lane >> 4, cl = lane & 15;
  const int wm = wv >> 1, wn = wv & 1;
  const int row0 = blockIdx.x * 128, col0 = blockIdx.y * 128;
  f4 acc[4][4];
#pragma unroll
  for (int i = 0; i < 4; ++i)
#pragma unroll
    for (int j = 0; j < 4; ++j) acc[i][j] = (f4){0.f, 0.f, 0.f, 0.f};

  for (int kt = 0; kt < 8; ++kt) {
#pragma unroll
    for (int j = 0; j < 4; ++j) {
      int ci = wv * 4 + j;
      int gci = ci * 64 + lane;
      int r = gci >> 3, cc = gci & 7;
      gl_lds16(Ag + ((size_t)(row0 + r) << 9) + kt * 64 + cc * 8, Al + ci * 512);
      gl_lds16(Bg + ((size_t)(col0 + r) << 9) + kt * 64 + cc * 8, Bl + ci * 512);
    }
    __syncthreads();
#pragma unroll
    for (int kk = 0; kk < 2; ++kk) {
      bf8 af[4], bb[4];
#pragma unroll
      for (int mf = 0; mf < 4; ++mf) {
        int r = wm * 64 + mf * 16 + cl;
        int cc = (kk * 4 + g) ^ (r & 7);
        af[mf] = *(const bf8*)(Al + r * 64 + cc * 8);
      }
#pragma unroll
      for (int nf = 0; nf < 4; ++nf) {
        int r = wn * 64 + nf * 16 + cl;
        int cc = (kk * 4 + g) ^ (r & 7);
        bb[nf] = *(const bf8*)(Bl + r * 64 + cc * 8);
      }
#pragma unroll
      for (int mf = 0; mf < 4; ++mf)
#pragma unroll
        for (int nf = 0; nf < 4; ++nf)
          acc[mf][nf] = __builtin_amdgcn_mfma_f32_16x16x32_bf16(af[mf], bb[nf], acc[mf][nf], 0, 0, 0);
    }
    __syncthreads();
  }

  if (EPI == 1) {
#pragma unroll
    for (int nf = 0; nf < 4; ++nf) {
      int col = col0 + wn * 64 + nf * 16 + cl;
      float bv = bias[col];
#pragma unroll
      for (int mf = 0; mf < 4; ++mf) {
#pragma unroll
        for (int j = 0; j < 4; ++j) {
          int row = row0 + wm * 64 + mf * 16 + 4 * g + j;  // C/D: col=lane&15, row=4*(lane>>4)+reg
          Of[((size_t)row << 9) + col] = acc[mf][nf][j] + bv;
        }
      }
    }
  } else {
    const int which = col0 >> 9;   // block-uniform
#pragma unroll
    for (int nf = 0; nf < 4; ++nf) {
      int col = col0 + wn * 64 + nf * 16 + cl;
      float bv = bias[col];
      int d = col & 63, h = (col >> 6) & 7;
#pragma unroll
      for (int mf = 0; mf < 4; ++mf) {
        int row = row0 + wm * 64 + mf * 16 + 4 * g;   // j = 0 row
        int b = row >> 11, s = row & 2047;
        size_t fb = ((size_t)b * 8 + h) * 131072;     // per-(b,h) fragment array
        if (which == 0) {
          // Q frag: [q16][kk][lane][8]; scale folds softmax 1/8 AND log2(e)
#pragma unroll
          for (int j = 0; j < 4; ++j) {
            int ss = s + j;
            size_t off = fb + (size_t)((ss >> 4) * 1024 + (d >> 5) * 512 +
                                       (((d >> 3) & 3) * 16 + (ss & 15)) * 8 + (d & 7));
            Oq[off] = f2bf((acc[mf][nf][j] + bv) * (0.125f * L2E));
          }
        } else if (which == 1) {
          // K frag: [kt][kk][ct][lane][8]
#pragma unroll
          for (int j = 0; j < 4; ++j) {
            int ss = s + j;
            size_t off = fb + (size_t)((ss >> 6) * 4096 + (d >> 5) * 2048 + ((ss >> 4) & 3) * 512 +
                                       (((d >> 3) & 3) * 16 + (ss & 15)) * 8 + (d & 7));
            Ok[off] = f2bf(acc[mf][nf][j] + bv);
          }
        } else {
          // V frag: [kt][kk][ct][lane][8]
          us4 o;
#pragma unroll
          for (int j = 0; j < 4; ++j) o[j] = f2bf(acc[mf][nf][j] + bv);
          size_t off = fb + (size_t)((s >> 6) * 4096 + ((s >> 5) & 1) * 2048 + (d >> 4) * 512 +
                                     ((((s >> 3) & 3) * 16) + (d & 15)) * 8 + (s & 7));
          *(us4*)(Ov + off) = o;
        }
      }
    }
  }
}

// ------------------------------- flash attention --------------------------------
// block = 4 waves = 4 BATCHES of the same (h, q16); 2048 blocks big-first.
// Swapped body, exp2 softmax, 2-deep A/B register pipeline across k-tiles.

#define LOADT(KF, VF, RT, RL, KT)                                             \
  do {                                                                        \
    const unsigned short* Kt_ = Kp + (KT) * 4096;                             \
    const unsigned short* Vt_ = Vp + (KT) * 4096;                             \
    _Pragma("unroll") for (int kk = 0; kk < 2; ++kk)                          \
      _Pragma("unroll") for (int ct = 0; ct < 4; ++ct)                        \
        KF[kk][ct] = *(const bf8*)(Kt_ + kk * 2048 + ct * 512 + lane * 8);    \
    _Pragma("unroll") for (int kk = 0; kk < 2; ++kk)                          \
      _Pragma("unroll") for (int ct = 0; ct < 4; ++ct)                        \
        VF[kk][ct] = *(const bf8*)(Vt_ + kk * 2048 + ct * 512 + lane * 8);    \
    if constexpr (RELT) {                                                     \
      const unsigned short* tb_ =                                             \
          relt + (((((size_t)h << 7) | q16) << 5) | (KT)) * 1024;             \
      _Pragma("unroll") for (int ct = 0; ct < 4; ++ct)                        \
        RT[ct] = *(const us4*)(tb_ + ((ct << 6) | lane) * 4);                 \
    } else {                                                                  \
      _Pragma("unroll") for (int ct = 0; ct < 4; ++ct)                        \
        RL[ct] = *(const float4*)(relp + ((size_t)qrow << 11) + ((KT) << 6) + \
                                  ct * 16 + g * 4);                           \
    }                                                                         \
  } while (0)

#define COMPT(KF, VF, RT, RL, KT)                                             \
  do {                                                                        \
    const int kb_ = (KT) << 6;                                                \
    f4 st[4];                                                                 \
    _Pragma("unroll") for (int ct = 0; ct < 4; ++ct)                          \
      st[ct] = (f4){0.f, 0.f, 0.f, 0.f};                                      \
    _Pragma("unroll") for (int kk = 0; kk < 2; ++kk)                          \
      _Pragma("unroll") for (int ct = 0; ct < 4; ++ct)                        \
        st[ct] = __builtin_amdgcn_mfma_f32_16x16x32_bf16(KF[kk][ct], qf[kk],  \
                                                         st[ct], 0, 0, 0);    \
    if constexpr (RELT) {                                                     \
      _Pragma("unroll") for (int ct = 0; ct < 4; ++ct)                        \
        _Pragma("unroll") for (int j = 0; j < 4; ++j)                         \
          st[ct][j] += __builtin_bit_cast(float, (unsigned)RT[ct][j] << 16);  \
    } else {                                                                  \
      _Pragma("unroll") for (int ct = 0; ct < 4; ++ct) {                      \
        st[ct][0] = fmaf(RL[ct].x, L2E, st[ct][0]);                           \
        st[ct][1] = fmaf(RL[ct].y, L2E, st[ct][1]);                           \
        st[ct][2] = fmaf(RL[ct].z, L2E, st[ct][2]);                           \
        st[ct][3] = fmaf(RL[ct].w, L2E, st[ct][3]);                           \
      }                                                                       \
    }                                                                         \
    if ((KT) == ktop) {                                                       \
      _Pragma("unroll") for (int ct = 0; ct < 4; ++ct) {                      \
        int kc0_ = kb_ + ct * 16 + 4 * g;                                     \
        _Pragma("unroll") for (int j = 0; j < 4; ++j)                         \
          if (kc0_ + j > qrow) st[ct][j] = -1e30f;                            \
      }                                                                       \
    }                                                                         \
    float m0_ = fmaxf(fmaxf(st[0][0], st[0][1]), fmaxf(st[0][2], st[0][3]));  \
    _Pragma("unroll") for (int ct = 1; ct < 4; ++ct)                          \
      m0_ = fmaxf(m0_, fmaxf(fmaxf(st[ct][0], st[ct][1]),                     \
                             fmaxf(st[ct][2], st[ct][3])));                   \
    m0_ = fmaxf(m0_, __shfl_xor(m0_, 16));                                    \
    m0_ = fmaxf(m0_, __shfl_xor(m0_, 32));                                    \
    float mn_ = fmaxf(mr, m0_);                                               \
    float al_ = exp2f(mr - mn_);                                              \
    mr = mn_;                                                                 \
    _Pragma("unroll") for (int ct = 0; ct < 4; ++ct)                          \
      _Pragma("unroll") for (int j = 0; j < 4; ++j)                           \
        st[ct][j] = exp2f(st[ct][j] - mn_);                                   \
    float rs_ = 0.f;                                                          \
    _Pragma("unroll") for (int ct = 0; ct < 4; ++ct)                          \
      rs_ += (st[ct][0] + st[ct][1]) + (st[ct][2] + st[ct][3]);               \
    rs_ += __shfl_xor(rs_, 16);                                               \
    rs_ += __shfl_xor(rs_, 32);                                               \
    lr = lr * al_ + rs_;                                                      \
    _Pragma("unroll") for (int ct = 0; ct < 4; ++ct) {                        \
      ot[ct][0] *= al_; ot[ct][1] *= al_; ot[ct][2] *= al_; ot[ct][3] *= al_; \
    }                                                                         \
    _Pragma("unroll") for (int ct = 0; ct < 4; ++ct) {                        \
      us4 pk_;                                                                \
      pk_[0] = cbf(st[ct][0]); pk_[1] = cbf(st[ct][1]);                       \
      pk_[2] = cbf(st[ct][2]); pk_[3] = cbf(st[ct][3]);                       \
      *(us4*)(pw + cl * 72 + ct * 16 + g * 4) = pk_;                          \
    }                                                                         \
    _Pragma("unroll") for (int kk = 0; kk < 2; ++kk) {                        \
      bf8 pf_ = __builtin_bit_cast(bf8,                                       \
                  *(const us8*)(pw + cl * 72 + kk * 32 + g * 8));             \
      _Pragma("unroll") for (int ct = 0; ct < 4; ++ct)                        \
        ot[ct] = __builtin_amdgcn_mfma_f32_16x16x32_bf16(VF[kk][ct], pf_,     \
                                                         ot[ct], 0, 0, 0);    \
    }                                                                         \
  } while (0)

template <bool RELT>
__global__ __launch_bounds__(256, 4)
void k_attn(const unsigned short* __restrict__ Qf, const unsigned short* __restrict__ Kf,
            const unsigned short* __restrict__ Vf, const float* __restrict__ rel,
            const unsigned short* __restrict__ relt, unsigned short* __restrict__ AO) {
  __shared__ __align__(16) unsigned short Pl[4][16 * 72];
  const int tid = threadIdx.x, wv = tid >> 6, lane = tid & 63, g = lane >> 4, cl = lane & 15;
  int bid = blockIdx.x;                        // 2048 blocks
  int h = bid & 7;                             // head's relt panel pinned to one XCD
  int rest = bid >> 3;                         // 0..255
  int q16 = 127 - (rest >> 1);                 // 127..0, big-first
  int b = ((rest & 1) << 2) | wv;              // 0..7
  const int rX = q16 << 4;
  const int ktop = q16 >> 2;                   // diagonal k-tile index
  const int qrow = rX + cl;                    // this lane's q-row (swapped layout)
  size_t fb = (((size_t)b << 3) + h) * 131072;
  const unsigned short* Qp = Qf + fb;
  const unsigned short* Kp = Kf + fb;
  const unsigned short* Vp = Vf + fb;
  const float* relp = rel + ((size_t)h << 22);
  unsigned short* pw = Pl[wv];

  bf8 qf[2];
#pragma unroll
  for (int kk = 0; kk < 2; ++kk)
    qf[kk] = *(const bf8*)(Qp + q16 * 1024 + kk * 512 + lane * 8);

  f4 ot[4];                                    // O^T frags: ot[ct][j] = O[q=cl][d=16ct+4g+j]
  float mr = -1e30f, lr = 0.f;
#pragma unroll
  for (int ct = 0; ct < 4; ++ct) ot[ct] = (f4){0.f, 0.f, 0.f, 0.f};

  // ---- 2-deep pipelined k-tile loop (named A/B buffers, unrolled-2) ----
  bf8 kfA[2][4], vfA[2][4], kfB[2][4], vfB[2][4];
  us4 rtA[4], rtB[4];
  float4 rlA[4], rlB[4];
  LOADT(kfA, vfA, rtA, rlA, 0);
  int kt = 0;
  for (;;) {
    if (kt + 1 <= ktop) LOADT(kfB, vfB, rtB, rlB, kt + 1);
    COMPT(kfA, vfA, rtA, rlA, kt);
    if (++kt > ktop) break;
    if (kt + 1 <= ktop) LOADT(kfA, vfA, rtA, rlA, kt + 1);
    COMPT(kfB, vfB, rtB, rlB, kt);
    if (++kt > ktop) break;
  }

  // ---- epilogue: O /= l; d = 16ct+4g+j -> chunk-swizzled us4 stores ----
  float inv = 1.0f / lr;
  const int s = qrow;
  unsigned short* aor = AO + (((size_t)b << 11) + s) * 512 + h * 64;
#pragma unroll
  for (int ct = 0; ct < 4; ++ct) {
    int chunk = 2 * ct + (g >> 1);
    int base = (4 * (g & 1)) | ((chunk ^ (s & 7)) << 3);
    us4 o;
    o[0] = cbf(ot[ct][0] * inv); o[1] = cbf(ot[ct][1] * inv);
    o[2] = cbf(ot[ct][2] * inv); o[3] = cbf(ot[ct][3] * inv);
    *(us4*)(aor + base) = o;
  }
}

// ------------------------------------ launch ------------------------------------
extern "C" void kernel_launch(void* const* d_in, const int* in_sizes, int n_in,
                              void* d_out, int out_size, void* d_ws, size_t ws_size,
                              hipStream_t stream) {
  const float* x    = (const float*)d_in[0];
  const float* Wqkv = (const float*)d_in[1];
  const float* bqkv = (const float*)d_in[2];
  const float* Wout = (const float*)d_in[3];
  const float* bout = (const float*)d_in[4];
  const float* rel  = (const float*)d_in[5];
  float* out = (float*)d_out;

  unsigned short* Qw  = (unsigned short*)d_ws;
  unsigned short* Kw  = Qw  + 8388608;
  unsigned short* Vw  = Kw  + 8388608;
  unsigned short* XA  = Vw  + 8388608;    // Xb (pre-attn) then AO (post-attn)
  unsigned short* WtQ = XA  + 8388608;
  unsigned short* WtO = WtQ + 786432;
  unsigned short* relt= WtO + 262144;
  const bool useT = ws_size >= (34603008ULL + 33554432ULL) * 2ULL;  // base + rel table

  k_convert_x<<<dim3(4096), dim3(256), 0, stream>>>(x, XA);
  k_transpose_w<<<dim3(16, 48), dim3(256), 0, stream>>>(Wqkv, WtQ, 1536);
  k_transpose_w<<<dim3(16, 16), dim3(256), 0, stream>>>(Wout, WtO, 512);
  if (useT) k_relconv<<<dim3(32768), dim3(256), 0, stream>>>(rel, relt);
  k_gemm<0><<<dim3(128, 12), dim3(256), 0, stream>>>(XA, WtQ, bqkv, nullptr, Qw, Kw, Vw);
  if (useT) k_attn<true ><<<dim3(2048), dim3(256), 0, stream>>>(Qw, Kw, Vw, rel, relt, XA);
  else      k_attn<false><<<dim3(2048), dim3(256), 0, stream>>>(Qw, Kw, Vw, rel, relt, XA);
  k_gemm<1><<<dim3(128, 4), dim3(256), 0, stream>>>(XA, WtO, bout, out, nullptr, nullptr, nullptr);
}

// Round 19
// 214.781 us; speedup vs baseline: 2.9185x; 2.9185x over previous
//
#include <hip/hip_runtime.h>
#include <cstdint>

// CausalSelfAttention fused pipeline, all-bf16 MFMA path.
// R19 = R17 (best: swapped-QK^T body, 4-batch-wave grid, relt L1-sharing) plus
// register-NEUTRAL additions only (R18's A/B double-buffer overflowed the 128
// budget -> allocator collapsed to 64-tier, 1.5GB spill):
//  (1) deferred K-reload: kf reloaded IN PLACE right after QK^T consumes it,
//      giving tile kt+1's K loads ~300cy of flight before their wait. 0 extra regs.
//  (2) exp2-domain softmax (validated R18): log2e folded into Q-scale + relt.
//  (3) s_setprio(1) around MFMA clusters (T5; independent-wave regime, m191 +4-7%).
// ws layout (ushort): Qf[8.39M] Kf[8.39M] Vf[8.39M] XbAO[8.39M] WtQ[786K] WtO[262K] [relt 33.55M]

#define DEVI __device__ __forceinline__

typedef __bf16 bf8 __attribute__((ext_vector_type(8)));
typedef float f4 __attribute__((ext_vector_type(4)));
typedef unsigned short us8 __attribute__((ext_vector_type(8)));
typedef unsigned short us4 __attribute__((ext_vector_type(4)));

typedef const unsigned int __attribute__((address_space(1))) gu32;
typedef unsigned int __attribute__((address_space(3))) lu32;

#define L2E 1.44269504088896f

DEVI unsigned short f2bf(float f) {  // RNE f32->bf16 (prep/GEMM epilogues)
  unsigned u = __builtin_bit_cast(unsigned, f);
  u += 0x7fffu + ((u >> 16) & 1u);
  return (unsigned short)(u >> 16);
}

DEVI unsigned short cbf(float f) {   // compiler-lowered cast (v_cvt_pk_bf16_f32 pairs)
  return __builtin_bit_cast(unsigned short, (__bf16)f);
}

DEVI void gl_lds16(const void* g, void* l) {
  __builtin_amdgcn_global_load_lds((gu32*)g, (lu32*)l, 16, 0, 0);
}

// ---------------- prep: x (f32 [16384][512]) -> bf16, chunk-swizzled ----------------
__global__ __launch_bounds__(256) void k_convert_x(const float* __restrict__ x,
                                                   unsigned short* __restrict__ xb) {
  int c = blockIdx.x * 256 + threadIdx.x;   // 1,048,576 chunks
  int row = c >> 6, cl = c & 63;
  const float* s = x + ((size_t)row << 9) + (cl << 3);
  float4 a = *(const float4*)s;
  float4 b = *(const float4*)(s + 4);
  us8 o;
  o[0]=f2bf(a.x); o[1]=f2bf(a.y); o[2]=f2bf(a.z); o[3]=f2bf(a.w);
  o[4]=f2bf(b.x); o[5]=f2bf(b.y); o[6]=f2bf(b.z); o[7]=f2bf(b.w);
  int p = (cl & ~7) | ((cl & 7) ^ (row & 7));
  *(us8*)(xb + ((size_t)row << 9) + (p << 3)) = o;
}

// ------------- prep: W [512][N] f32 -> Wt [N][512] bf16, chunk-swizzled -------------
__global__ __launch_bounds__(256) void k_transpose_w(const float* __restrict__ W,
                                                     unsigned short* __restrict__ Wt, int N) {
  __shared__ float t[32][33];
  int k0 = blockIdx.x * 32, n0 = blockIdx.y * 32;
  int tx = threadIdx.x & 31, ty = threadIdx.x >> 5;
#pragma unroll
  for (int r = 0; r < 4; ++r)
    t[ty + r * 8][tx] = W[(size_t)(k0 + ty + r * 8) * N + n0 + tx];
  __syncthreads();
#pragma unroll
  for (int r = 0; r < 4; ++r) {
    int n = n0 + ty + r * 8, k = k0 + tx;
    int k2 = (k & ~63) | ((((k >> 3) & 7) ^ (n & 7)) << 3) | (k & 7);
    Wt[((size_t)n << 9) + k2] = f2bf(t[tx][ty + r * 8]);
  }
}

// ---- prep: rel f32 [h][q][k] -> bf16 table, SWAPPED frag order, PRE-SCALED by log2e ----
// relt[h][q16][kt][ct][lane][j] = rel[q16*16+(lane&15)][kt*64+ct*16+4*(lane>>4)+j] * L2E
__global__ __launch_bounds__(256) void k_relconv(const float* __restrict__ rel,
                                                 unsigned short* __restrict__ relt) {
  int t = blockIdx.x * 256 + threadIdx.x;   // 8.39M threads
  int lane = t & 63, ct = (t >> 6) & 3, kt = (t >> 8) & 31, q16 = (t >> 13) & 127, h = t >> 20;
  if (kt > (q16 >> 2)) return;              // above-diagonal tiles never read
  int row = (q16 << 4) + (lane & 15);
  int col = (kt << 6) + (ct << 4) + ((lane >> 4) << 2);
  float4 v = *(const float4*)(rel + ((size_t)h << 22) + ((size_t)row << 11) + col);
  us4 o;
  o[0] = f2bf(v.x * L2E); o[1] = f2bf(v.y * L2E);
  o[2] = f2bf(v.z * L2E); o[3] = f2bf(v.w * L2E);
  size_t idx = ((((((size_t)h << 7) | q16) << 5) | kt) << 2 | ct) << 6 | lane;
  *(us4*)(relt + (idx << 2)) = o;
}

// ---------------- GEMM: C[M][col] = A[M][512] * Bt[col][512]^T + bias ----------------
template <int EPI>
__global__ __launch_bounds__(256, 2)
void k_gemm(const unsigned short* __restrict__ Ag, const unsigned short* __restrict__ Bg,
            const float* __restrict__ bias, float* __restrict__ Of,
            unsigned short* __restrict__ Oq, unsigned short* __restrict__ Ok,
            unsigned short* __restrict__ Ov) {
  __shared__ __align__(16) unsigned short lds[128 * 64 * 2];
  unsigned short* Al = lds;
  unsigned short* Bl = lds + 128 * 64;
  const int tid = threadIdx.x, wv = tid >> 6, lane = tid & 63, g = lane >> 4, cl = lane & 15;
  const int wm = wv >> 1, wn = wv & 1;
  const int row0 = blockIdx.x * 128, col0 = blockIdx.y * 128;
  f4 acc[4][4];
#pragma unroll
  for (int i = 0; i < 4; ++i)
#pragma unroll
    for (int j = 0; j < 4; ++j) acc[i][j] = (f4){0.f, 0.f, 0.f, 0.f};

  for (int kt = 0; kt < 8; ++kt) {
#pragma unroll
    for (int j = 0; j < 4; ++j) {
      int ci = wv * 4 + j;
      int gci = ci * 64 + lane;
      int r = gci >> 3, cc = gci & 7;
      gl_lds16(Ag + ((size_t)(row0 + r) << 9) + kt * 64 + cc * 8, Al + ci * 512);
      gl_lds16(Bg + ((size_t)(col0 + r) << 9) + kt * 64 + cc * 8, Bl + ci * 512);
    }
    __syncthreads();
#pragma unroll
    for (int kk = 0; kk < 2; ++kk) {
      bf8 af[4], bb[4];
#pragma unroll
      for (int mf = 0; mf < 4; ++mf) {
        int r = wm * 64 + mf * 16 + cl;
        int cc = (kk * 4 + g) ^ (r & 7);
        af[mf] = *(const bf8*)(Al + r * 64 + cc * 8);
      }
#pragma unroll
      for (int nf = 0; nf < 4; ++nf) {
        int r = wn * 64 + nf * 16 + cl;
        int cc = (kk * 4 + g) ^ (r & 7);
        bb[nf] = *(const bf8*)(Bl + r * 64 + cc * 8);
      }
#pragma unroll
      for (int mf = 0; mf < 4; ++mf)
#pragma unroll
        for (int nf = 0; nf < 4; ++nf)
          acc[mf][nf] = __builtin_amdgcn_mfma_f32_16x16x32_bf16(af[mf], bb[nf], acc[mf][nf], 0, 0, 0);
    }
    __syncthreads();
  }

  if (EPI == 1) {
#pragma unroll
    for (int nf = 0; nf < 4; ++nf) {
      int col = col0 + wn * 64 + nf * 16 + cl;
      float bv = bias[col];
#pragma unroll
      for (int mf = 0; mf < 4; ++mf) {
#pragma unroll
        for (int j = 0; j < 4; ++j) {
          int row = row0 + wm * 64 + mf * 16 + 4 * g + j;  // C/D: col=lane&15, row=4*(lane>>4)+reg
          Of[((size_t)row << 9) + col] = acc[mf][nf][j] + bv;
        }
      }
    }
  } else {
    const int which = col0 >> 9;   // block-uniform
#pragma unroll
    for (int nf = 0; nf < 4; ++nf) {
      int col = col0 + wn * 64 + nf * 16 + cl;
      float bv = bias[col];
      int d = col & 63, h = (col >> 6) & 7;
#pragma unroll
      for (int mf = 0; mf < 4; ++mf) {
        int row = row0 + wm * 64 + mf * 16 + 4 * g;   // j = 0 row
        int b = row >> 11, s = row & 2047;
        size_t fb = ((size_t)b * 8 + h) * 131072;     // per-(b,h) fragment array
        if (which == 0) {
          // Q frag: [q16][kk][lane][8]; scale folds softmax 1/8 AND log2(e)
#pragma unroll
          for (int j = 0; j < 4; ++j) {
            int ss = s + j;
            size_t off = fb + (size_t)((ss >> 4) * 1024 + (d >> 5) * 512 +
                                       (((d >> 3) & 3) * 16 + (ss & 15)) * 8 + (d & 7));
            Oq[off] = f2bf((acc[mf][nf][j] + bv) * (0.125f * L2E));
          }
        } else if (which == 1) {
          // K frag: [kt][kk][ct][lane][8]
#pragma unroll
          for (int j = 0; j < 4; ++j) {
            int ss = s + j;
            size_t off = fb + (size_t)((ss >> 6) * 4096 + (d >> 5) * 2048 + ((ss >> 4) & 3) * 512 +
                                       (((d >> 3) & 3) * 16 + (ss & 15)) * 8 + (d & 7));
            Ok[off] = f2bf(acc[mf][nf][j] + bv);
          }
        } else {
          // V frag: [kt][kk][ct][lane][8]
          us4 o;
#pragma unroll
          for (int j = 0; j < 4; ++j) o[j] = f2bf(acc[mf][nf][j] + bv);
          size_t off = fb + (size_t)((s >> 6) * 4096 + ((s >> 5) & 1) * 2048 + (d >> 4) * 512 +
                                     ((((s >> 3) & 3) * 16) + (d & 15)) * 8 + (s & 7));
          *(us4*)(Ov + off) = o;
        }
      }
    }
  }
}

// ------------------------------- flash attention --------------------------------
// block = 4 waves = 4 BATCHES of the same (h, q16); 2048 blocks big-first.
// Swapped body, exp2 softmax, deferred in-place K reload, setprio around MFMA.
template <bool RELT>
__global__ __launch_bounds__(256, 4)
void k_attn(const unsigned short* __restrict__ Qf, const unsigned short* __restrict__ Kf,
            const unsigned short* __restrict__ Vf, const float* __restrict__ rel,
            const unsigned short* __restrict__ relt, unsigned short* __restrict__ AO) {
  __shared__ __align__(16) unsigned short Pl[4][16 * 72];
  const int tid = threadIdx.x, wv = tid >> 6, lane = tid & 63, g = lane >> 4, cl = lane & 15;
  int bid = blockIdx.x;                        // 2048 blocks
  int h = bid & 7;                             // head's relt panel pinned to one XCD
  int rest = bid >> 3;                         // 0..255
  int q16 = 127 - (rest >> 1);                 // 127..0, big-first
  int b = ((rest & 1) << 2) | wv;              // 0..7
  const int rX = q16 << 4;
  const int ktop = q16 >> 2;                   // diagonal k-tile index
  const int qrow = rX + cl;                    // this lane's q-row (swapped layout)
  size_t fb = (((size_t)b << 3) + h) * 131072;
  const unsigned short* Qp = Qf + fb;
  const unsigned short* Kp = Kf + fb;
  const unsigned short* Vp = Vf + fb;
  const float* relp = rel + ((size_t)h << 22);
  unsigned short* pw = Pl[wv];

  bf8 qf[2];
#pragma unroll
  for (int kk = 0; kk < 2; ++kk)
    qf[kk] = *(const bf8*)(Qp + q16 * 1024 + kk * 512 + lane * 8);

  f4 ot[4];                                    // O^T frags: ot[ct][j] = O[q=cl][d=16ct+4g+j]
  float mr = -1e30f, lr = 0.f;
#pragma unroll
  for (int ct = 0; ct < 4; ++ct) ot[ct] = (f4){0.f, 0.f, 0.f, 0.f};

  // prologue: K(0) into kf (single buffer, reloaded in place each tile)
  bf8 kf[2][4];
#pragma unroll
  for (int kk = 0; kk < 2; ++kk)
#pragma unroll
    for (int ct = 0; ct < 4; ++ct)
      kf[kk][ct] = *(const bf8*)(Kp + kk * 2048 + ct * 512 + lane * 8);

  for (int kt = 0; kt <= ktop; ++kt) {
    const int kb = kt << 6;
    const unsigned short* Vt = Vp + kt * 4096;
    // ---- V(kt) + rel(kt) issue first (consumed after QK^T; FIFO keeps K wait tight) ----
    bf8 vf[2][4];
#pragma unroll
    for (int kk = 0; kk < 2; ++kk)
#pragma unroll
      for (int ct = 0; ct < 4; ++ct)
        vf[kk][ct] = *(const bf8*)(Vt + kk * 2048 + ct * 512 + lane * 8);
    us4 rt4[4];
    float4 rl4[4];
    if constexpr (RELT) {
      const unsigned short* tb = relt + (((((size_t)h << 7) | q16) << 5) | kt) * 1024;
#pragma unroll
      for (int ct = 0; ct < 4; ++ct)
        rt4[ct] = *(const us4*)(tb + ((ct << 6) | lane) * 4);
    } else {
#pragma unroll
      for (int ct = 0; ct < 4; ++ct)
        rl4[ct] = *(const float4*)(relp + ((size_t)qrow << 11) + kb + ct * 16 + g * 4);
    }
    // ---- QK^T (waits kf, which has been in flight since mid-previous-tile) ----
    f4 st[4];
#pragma unroll
    for (int ct = 0; ct < 4; ++ct) st[ct] = (f4){0.f, 0.f, 0.f, 0.f};
    __builtin_amdgcn_s_setprio(1);
#pragma unroll
    for (int kk = 0; kk < 2; ++kk)
#pragma unroll
      for (int ct = 0; ct < 4; ++ct)
        st[ct] = __builtin_amdgcn_mfma_f32_16x16x32_bf16(kf[kk][ct], qf[kk], st[ct], 0, 0, 0);
    __builtin_amdgcn_s_setprio(0);
    // ---- deferred K reload: K(kt+1) into kf NOW (0 extra regs, ~300cy of flight) ----
    if (kt < ktop) {
      const unsigned short* Kn = Kp + (kt + 1) * 4096;
#pragma unroll
      for (int kk = 0; kk < 2; ++kk)
#pragma unroll
        for (int ct = 0; ct < 4; ++ct)
          kf[kk][ct] = *(const bf8*)(Kn + kk * 2048 + ct * 512 + lane * 8);
    }
    // ---- rel_pos add (waits rel only; K(kt+1) stays in flight per FIFO) ----
    if constexpr (RELT) {
#pragma unroll
      for (int ct = 0; ct < 4; ++ct)
#pragma unroll
        for (int j = 0; j < 4; ++j)
          st[ct][j] += __builtin_bit_cast(float, (unsigned)rt4[ct][j] << 16);
    } else {
#pragma unroll
      for (int ct = 0; ct < 4; ++ct) {
        st[ct][0] = fmaf(rl4[ct].x, L2E, st[ct][0]);
        st[ct][1] = fmaf(rl4[ct].y, L2E, st[ct][1]);
        st[ct][2] = fmaf(rl4[ct].z, L2E, st[ct][2]);
        st[ct][3] = fmaf(rl4[ct].w, L2E, st[ct][3]);
      }
    }
    // ---- causal mask (diagonal tile only) ----
    if (kt == ktop) {
#pragma unroll
      for (int ct = 0; ct < 4; ++ct) {
        int kc0 = kb + ct * 16 + 4 * g;
#pragma unroll
        for (int j = 0; j < 4; ++j)
          if (kc0 + j > qrow) st[ct][j] = -1e30f;
      }
    }
    // ---- online softmax (exp2 domain): in-lane tree + 2 shfl; lane scalars ----
    float m0 = fmaxf(fmaxf(st[0][0], st[0][1]), fmaxf(st[0][2], st[0][3]));
#pragma unroll
    for (int ct = 1; ct < 4; ++ct)
      m0 = fmaxf(m0, fmaxf(fmaxf(st[ct][0], st[ct][1]), fmaxf(st[ct][2], st[ct][3])));
    m0 = fmaxf(m0, __shfl_xor(m0, 16));
    m0 = fmaxf(m0, __shfl_xor(m0, 32));
    float mn = fmaxf(mr, m0);
    float al = exp2f(mr - mn);
    mr = mn;
#pragma unroll
    for (int ct = 0; ct < 4; ++ct)
#pragma unroll
      for (int j = 0; j < 4; ++j) st[ct][j] = exp2f(st[ct][j] - mn);
    float rs = 0.f;
#pragma unroll
    for (int ct = 0; ct < 4; ++ct)
      rs += (st[ct][0] + st[ct][1]) + (st[ct][2] + st[ct][3]);
    rs += __shfl_xor(rs, 16);
    rs += __shfl_xor(rs, 32);
    lr = lr * al + rs;
#pragma unroll
    for (int ct = 0; ct < 4; ++ct) {
      ot[ct][0] *= al; ot[ct][1] *= al; ot[ct][2] *= al; ot[ct][3] *= al;
    }
    // ---- P -> LDS rows [q=cl][k]: 4x ds_write_b64 (wave-private, in-order) ----
#pragma unroll
    for (int ct = 0; ct < 4; ++ct) {
      us4 pk;
      pk[0] = cbf(st[ct][0]); pk[1] = cbf(st[ct][1]);
      pk[2] = cbf(st[ct][2]); pk[3] = cbf(st[ct][3]);
      *(us4*)(pw + cl * 72 + ct * 16 + g * 4) = pk;
    }
    // ---- PV: ot += mfma(V_frag, P_frag); waits vf (in flight since tile top) ----
    __builtin_amdgcn_s_setprio(1);
#pragma unroll
    for (int kk = 0; kk < 2; ++kk) {
      bf8 pf = __builtin_bit_cast(bf8, *(const us8*)(pw + cl * 72 + kk * 32 + g * 8));
#pragma unroll
      for (int ct = 0; ct < 4; ++ct)
        ot[ct] = __builtin_amdgcn_mfma_f32_16x16x32_bf16(vf[kk][ct], pf, ot[ct], 0, 0, 0);
    }
    __builtin_amdgcn_s_setprio(0);
  }
  // ---- epilogue: O /= l; d = 16ct+4g+j -> chunk-swizzled us4 stores ----
  float inv = 1.0f / lr;
  const int s = qrow;
  unsigned short* aor = AO + (((size_t)b << 11) + s) * 512 + h * 64;
#pragma unroll
  for (int ct = 0; ct < 4; ++ct) {
    int chunk = 2 * ct + (g >> 1);
    int base = (4 * (g & 1)) | ((chunk ^ (s & 7)) << 3);
    us4 o;
    o[0] = cbf(ot[ct][0] * inv); o[1] = cbf(ot[ct][1] * inv);
    o[2] = cbf(ot[ct][2] * inv); o[3] = cbf(ot[ct][3] * inv);
    *(us4*)(aor + base) = o;
  }
}

// ------------------------------------ launch ------------------------------------
extern "C" void kernel_launch(void* const* d_in, const int* in_sizes, int n_in,
                              void* d_out, int out_size, void* d_ws, size_t ws_size,
                              hipStream_t stream) {
  const float* x    = (const float*)d_in[0];
  const float* Wqkv = (const float*)d_in[1];
  const float* bqkv = (const float*)d_in[2];
  const float* Wout = (const float*)d_in[3];
  const float* bout = (const float*)d_in[4];
  const float* rel  = (const float*)d_in[5];
  float* out = (float*)d_out;

  unsigned short* Qw  = (unsigned short*)d_ws;
  unsigned short* Kw  = Qw  + 8388608;
  unsigned short* Vw  = Kw  + 8388608;
  unsigned short* XA  = Vw  + 8388608;    // Xb (pre-attn) then AO (post-attn)
  unsigned short* WtQ = XA  + 8388608;
  unsigned short* WtO = WtQ + 786432;
  unsigned short* relt= WtO + 262144;
  const bool useT = ws_size >= (34603008ULL + 33554432ULL) * 2ULL;  // base + rel table

  k_convert_x<<<dim3(4096), dim3(256), 0, stream>>>(x, XA);
  k_transpose_w<<<dim3(16, 48), dim3(256), 0, stream>>>(Wqkv, WtQ, 1536);
  k_transpose_w<<<dim3(16, 16), dim3(256), 0, stream>>>(Wout, WtO, 512);
  if (useT) k_relconv<<<dim3(32768), dim3(256), 0, stream>>>(rel, relt);
  k_gemm<0><<<dim3(128, 12), dim3(256), 0, stream>>>(XA, WtQ, bqkv, nullptr, Qw, Kw, Vw);
  if (useT) k_attn<true ><<<dim3(2048), dim3(256), 0, stream>>>(Qw, Kw, Vw, rel, relt, XA);
  else      k_attn<false><<<dim3(2048), dim3(256), 0, stream>>>(Qw, Kw, Vw, rel, relt, XA);
  k_gemm<1><<<dim3(128, 4), dim3(256), 0, stream>>>(XA, WtO, bout, out, nullptr, nullptr, nullptr);
}

// Round 20
// 199.720 us; speedup vs baseline: 3.1386x; 1.0754x over previous
//
#include <hip/hip_runtime.h>
#include <cstdint>

// CausalSelfAttention fused pipeline, all-bf16 MFMA path.
// R20 = R17 EXACTLY (best attn: 105.5us — swapped-QK^T body, 4-batch-wave grid,
// relt L1-sharing, loads-at-tile-top, launch_bounds(256,4)) plus ONE change:
// exp2-domain softmax (log2e folded into Q-scale + relt at prep; __expf->exp2f,
// 17 fewer VALU ops/tile). R18/R19 lessons: ANY register-pressure change (A/B
// dbuf, early K-reload) collapses the allocator to the 64-tier and spills into
// the serial chain; setprio while waiting on own loads hurts. Keep R17's shape.
// ws layout (ushort): Qf[8.39M] Kf[8.39M] Vf[8.39M] XbAO[8.39M] WtQ[786K] WtO[262K] [relt 33.55M]

#define DEVI __device__ __forceinline__

typedef __bf16 bf8 __attribute__((ext_vector_type(8)));
typedef float f4 __attribute__((ext_vector_type(4)));
typedef unsigned short us8 __attribute__((ext_vector_type(8)));
typedef unsigned short us4 __attribute__((ext_vector_type(4)));

typedef const unsigned int __attribute__((address_space(1))) gu32;
typedef unsigned int __attribute__((address_space(3))) lu32;

#define L2E 1.44269504088896f

DEVI unsigned short f2bf(float f) {  // RNE f32->bf16 (prep/GEMM epilogues)
  unsigned u = __builtin_bit_cast(unsigned, f);
  u += 0x7fffu + ((u >> 16) & 1u);
  return (unsigned short)(u >> 16);
}

DEVI unsigned short cbf(float f) {   // compiler-lowered cast (v_cvt_pk_bf16_f32 pairs)
  return __builtin_bit_cast(unsigned short, (__bf16)f);
}

DEVI void gl_lds16(const void* g, void* l) {
  __builtin_amdgcn_global_load_lds((gu32*)g, (lu32*)l, 16, 0, 0);
}

// ---------------- prep: x (f32 [16384][512]) -> bf16, chunk-swizzled ----------------
__global__ __launch_bounds__(256) void k_convert_x(const float* __restrict__ x,
                                                   unsigned short* __restrict__ xb) {
  int c = blockIdx.x * 256 + threadIdx.x;   // 1,048,576 chunks
  int row = c >> 6, cl = c & 63;
  const float* s = x + ((size_t)row << 9) + (cl << 3);
  float4 a = *(const float4*)s;
  float4 b = *(const float4*)(s + 4);
  us8 o;
  o[0]=f2bf(a.x); o[1]=f2bf(a.y); o[2]=f2bf(a.z); o[3]=f2bf(a.w);
  o[4]=f2bf(b.x); o[5]=f2bf(b.y); o[6]=f2bf(b.z); o[7]=f2bf(b.w);
  int p = (cl & ~7) | ((cl & 7) ^ (row & 7));
  *(us8*)(xb + ((size_t)row << 9) + (p << 3)) = o;
}

// ------------- prep: W [512][N] f32 -> Wt [N][512] bf16, chunk-swizzled -------------
__global__ __launch_bounds__(256) void k_transpose_w(const float* __restrict__ W,
                                                     unsigned short* __restrict__ Wt, int N) {
  __shared__ float t[32][33];
  int k0 = blockIdx.x * 32, n0 = blockIdx.y * 32;
  int tx = threadIdx.x & 31, ty = threadIdx.x >> 5;
#pragma unroll
  for (int r = 0; r < 4; ++r)
    t[ty + r * 8][tx] = W[(size_t)(k0 + ty + r * 8) * N + n0 + tx];
  __syncthreads();
#pragma unroll
  for (int r = 0; r < 4; ++r) {
    int n = n0 + ty + r * 8, k = k0 + tx;
    int k2 = (k & ~63) | ((((k >> 3) & 7) ^ (n & 7)) << 3) | (k & 7);
    Wt[((size_t)n << 9) + k2] = f2bf(t[tx][ty + r * 8]);
  }
}

// ---- prep: rel f32 [h][q][k] -> bf16 table, SWAPPED frag order, PRE-SCALED by log2e ----
// relt[h][q16][kt][ct][lane][j] = rel[q16*16+(lane&15)][kt*64+ct*16+4*(lane>>4)+j] * L2E
__global__ __launch_bounds__(256) void k_relconv(const float* __restrict__ rel,
                                                 unsigned short* __restrict__ relt) {
  int t = blockIdx.x * 256 + threadIdx.x;   // 8.39M threads
  int lane = t & 63, ct = (t >> 6) & 3, kt = (t >> 8) & 31, q16 = (t >> 13) & 127, h = t >> 20;
  if (kt > (q16 >> 2)) return;              // above-diagonal tiles never read
  int row = (q16 << 4) + (lane & 15);
  int col = (kt << 6) + (ct << 4) + ((lane >> 4) << 2);
  float4 v = *(const float4*)(rel + ((size_t)h << 22) + ((size_t)row << 11) + col);
  us4 o;
  o[0] = f2bf(v.x * L2E); o[1] = f2bf(v.y * L2E);
  o[2] = f2bf(v.z * L2E); o[3] = f2bf(v.w * L2E);
  size_t idx = ((((((size_t)h << 7) | q16) << 5) | kt) << 2 | ct) << 6 | lane;
  *(us4*)(relt + (idx << 2)) = o;
}

// ---------------- GEMM: C[M][col] = A[M][512] * Bt[col][512]^T + bias ----------------
template <int EPI>
__global__ __launch_bounds__(256, 2)
void k_gemm(const unsigned short* __restrict__ Ag, const unsigned short* __restrict__ Bg,
            const float* __restrict__ bias, float* __restrict__ Of,
            unsigned short* __restrict__ Oq, unsigned short* __restrict__ Ok,
            unsigned short* __restrict__ Ov) {
  __shared__ __align__(16) unsigned short lds[128 * 64 * 2];
  unsigned short* Al = lds;
  unsigned short* Bl = lds + 128 * 64;
  const int tid = threadIdx.x, wv = tid >> 6, lane = tid & 63, g = lane >> 4, cl = lane & 15;
  const int wm = wv >> 1, wn = wv & 1;
  const int row0 = blockIdx.x * 128, col0 = blockIdx.y * 128;
  f4 acc[4][4];
#pragma unroll
  for (int i = 0; i < 4; ++i)
#pragma unroll
    for (int j = 0; j < 4; ++j) acc[i][j] = (f4){0.f, 0.f, 0.f, 0.f};

  for (int kt = 0; kt < 8; ++kt) {
#pragma unroll
    for (int j = 0; j < 4; ++j) {
      int ci = wv * 4 + j;
      int gci = ci * 64 + lane;
      int r = gci >> 3, cc = gci & 7;
      gl_lds16(Ag + ((size_t)(row0 + r) << 9) + kt * 64 + cc * 8, Al + ci * 512);
      gl_lds16(Bg + ((size_t)(col0 + r) << 9) + kt * 64 + cc * 8, Bl + ci * 512);
    }
    __syncthreads();
#pragma unroll
    for (int kk = 0; kk < 2; ++kk) {
      bf8 af[4], bb[4];
#pragma unroll
      for (int mf = 0; mf < 4; ++mf) {
        int r = wm * 64 + mf * 16 + cl;
        int cc = (kk * 4 + g) ^ (r & 7);
        af[mf] = *(const bf8*)(Al + r * 64 + cc * 8);
      }
#pragma unroll
      for (int nf = 0; nf < 4; ++nf) {
        int r = wn * 64 + nf * 16 + cl;
        int cc = (kk * 4 + g) ^ (r & 7);
        bb[nf] = *(const bf8*)(Bl + r * 64 + cc * 8);
      }
#pragma unroll
      for (int mf = 0; mf < 4; ++mf)
#pragma unroll
        for (int nf = 0; nf < 4; ++nf)
          acc[mf][nf] = __builtin_amdgcn_mfma_f32_16x16x32_bf16(af[mf], bb[nf], acc[mf][nf], 0, 0, 0);
    }
    __syncthreads();
  }

  if (EPI == 1) {
#pragma unroll
    for (int nf = 0; nf < 4; ++nf) {
      int col = col0 + wn * 64 + nf * 16 + cl;
      float bv = bias[col];
#pragma unroll
      for (int mf = 0; mf < 4; ++mf) {
#pragma unroll
        for (int j = 0; j < 4; ++j) {
          int row = row0 + wm * 64 + mf * 16 + 4 * g + j;  // C/D: col=lane&15, row=4*(lane>>4)+reg
          Of[((size_t)row << 9) + col] = acc[mf][nf][j] + bv;
        }
      }
    }
  } else {
    const int which = col0 >> 9;   // block-uniform
#pragma unroll
    for (int nf = 0; nf < 4; ++nf) {
      int col = col0 + wn * 64 + nf * 16 + cl;
      float bv = bias[col];
      int d = col & 63, h = (col >> 6) & 7;
#pragma unroll
      for (int mf = 0; mf < 4; ++mf) {
        int row = row0 + wm * 64 + mf * 16 + 4 * g;   // j = 0 row
        int b = row >> 11, s = row & 2047;
        size_t fb = ((size_t)b * 8 + h) * 131072;     // per-(b,h) fragment array
        if (which == 0) {
          // Q frag: [q16][kk][lane][8]; scale folds softmax 1/8 AND log2(e)
#pragma unroll
          for (int j = 0; j < 4; ++j) {
            int ss = s + j;
            size_t off = fb + (size_t)((ss >> 4) * 1024 + (d >> 5) * 512 +
                                       (((d >> 3) & 3) * 16 + (ss & 15)) * 8 + (d & 7));
            Oq[off] = f2bf((acc[mf][nf][j] + bv) * (0.125f * L2E));
          }
        } else if (which == 1) {
          // K frag: [kt][kk][ct][lane][8]
#pragma unroll
          for (int j = 0; j < 4; ++j) {
            int ss = s + j;
            size_t off = fb + (size_t)((ss >> 6) * 4096 + (d >> 5) * 2048 + ((ss >> 4) & 3) * 512 +
                                       (((d >> 3) & 3) * 16 + (ss & 15)) * 8 + (d & 7));
            Ok[off] = f2bf(acc[mf][nf][j] + bv);
          }
        } else {
          // V frag: [kt][kk][ct][lane][8]
          us4 o;
#pragma unroll
          for (int j = 0; j < 4; ++j) o[j] = f2bf(acc[mf][nf][j] + bv);
          size_t off = fb + (size_t)((s >> 6) * 4096 + ((s >> 5) & 1) * 2048 + (d >> 4) * 512 +
                                     ((((s >> 3) & 3) * 16) + (d & 15)) * 8 + (s & 7));
          *(us4*)(Ov + off) = o;
        }
      }
    }
  }
}

// ------------------------------- flash attention --------------------------------
// block = 4 waves = 4 BATCHES of the same (h, q16) slab; 2048 blocks big-first.
// SWAPPED tile body: st = mfma(K,Q) -> lane owns q-row (q=cl), k=16ct+4g+j.
// Softmax (exp2 domain): in-lane trees + 2 shfl; m/l lane scalars. P via LDS
// [q][k] rows: 4 ds_write_b64 + 2 ds_read_b128. PV: ot = mfma(V,P).
// relt tiles identical across the block's 4 waves -> L1 broadcast.
template <bool RELT>
__global__ __launch_bounds__(256, 4)
void k_attn(const unsigned short* __restrict__ Qf, const unsigned short* __restrict__ Kf,
            const unsigned short* __restrict__ Vf, const float* __restrict__ rel,
            const unsigned short* __restrict__ relt, unsigned short* __restrict__ AO) {
  __shared__ __align__(16) unsigned short Pl[4][16 * 72];
  const int tid = threadIdx.x, wv = tid >> 6, lane = tid & 63, g = lane >> 4, cl = lane & 15;
  int bid = blockIdx.x;                        // 2048 blocks
  int h = bid & 7;                             // head's relt panel pinned to one XCD
  int rest = bid >> 3;                         // 0..255
  int q16 = 127 - (rest >> 1);                 // 127..0, big-first
  int b = ((rest & 1) << 2) | wv;              // 0..7
  const int rX = q16 << 4;
  const int ktop = q16 >> 2;                   // diagonal k-tile index
  const int qrow = rX + cl;                    // this lane's q-row (swapped layout)
  size_t fb = (((size_t)b << 3) + h) * 131072;
  const unsigned short* Qp = Qf + fb;
  const unsigned short* Kp = Kf + fb;
  const unsigned short* Vp = Vf + fb;
  const float* relp = rel + ((size_t)h << 22);
  unsigned short* pw = Pl[wv];

  bf8 qf[2];
#pragma unroll
  for (int kk = 0; kk < 2; ++kk)
    qf[kk] = *(const bf8*)(Qp + q16 * 1024 + kk * 512 + lane * 8);

  f4 ot[4];                                    // O^T frags: ot[ct][j] = O[q=cl][d=16ct+4g+j]
  float mr = -1e30f, lr = 0.f;
#pragma unroll
  for (int ct = 0; ct < 4; ++ct) ot[ct] = (f4){0.f, 0.f, 0.f, 0.f};

  for (int kt = 0; kt <= ktop; ++kt) {
    const int kb = kt << 6;
    const unsigned short* Kt = Kp + kt * 4096;
    const unsigned short* Vt = Vp + kt * 4096;
    // ---- ALL loads up front: K (QK^T dep), then V, then rel (FIFO vmcnt) ----
    bf8 kf[2][4], vf[2][4];
#pragma unroll
    for (int kk = 0; kk < 2; ++kk)
#pragma unroll
      for (int ct = 0; ct < 4; ++ct)
        kf[kk][ct] = *(const bf8*)(Kt + kk * 2048 + ct * 512 + lane * 8);
#pragma unroll
    for (int kk = 0; kk < 2; ++kk)
#pragma unroll
      for (int ct = 0; ct < 4; ++ct)
        vf[kk][ct] = *(const bf8*)(Vt + kk * 2048 + ct * 512 + lane * 8);
    us4 rt4[4];
    float4 rl4[4];
    if constexpr (RELT) {
      const unsigned short* tb = relt + (((((size_t)h << 7) | q16) << 5) | kt) * 1024;
#pragma unroll
      for (int ct = 0; ct < 4; ++ct)
        rt4[ct] = *(const us4*)(tb + ((ct << 6) | lane) * 4);
    } else {
#pragma unroll
      for (int ct = 0; ct < 4; ++ct)
        rl4[ct] = *(const float4*)(relp + ((size_t)qrow << 11) + kb + ct * 16 + g * 4);
    }
    // ---- QK^T SWAPPED: st[ct][j] = S[q=cl][k = kb + 16ct + 4g + j] ----
    f4 st[4];
#pragma unroll
    for (int ct = 0; ct < 4; ++ct) st[ct] = (f4){0.f, 0.f, 0.f, 0.f};
#pragma unroll
    for (int kk = 0; kk < 2; ++kk)
#pragma unroll
      for (int ct = 0; ct < 4; ++ct)
        st[ct] = __builtin_amdgcn_mfma_f32_16x16x32_bf16(kf[kk][ct], qf[kk], st[ct], 0, 0, 0);
    // ---- rel_pos add (already in log2e domain) ----
    if constexpr (RELT) {
#pragma unroll
      for (int ct = 0; ct < 4; ++ct)
#pragma unroll
        for (int j = 0; j < 4; ++j)
          st[ct][j] += __builtin_bit_cast(float, (unsigned)rt4[ct][j] << 16);
    } else {
#pragma unroll
      for (int ct = 0; ct < 4; ++ct) {
        st[ct][0] = fmaf(rl4[ct].x, L2E, st[ct][0]);
        st[ct][1] = fmaf(rl4[ct].y, L2E, st[ct][1]);
        st[ct][2] = fmaf(rl4[ct].z, L2E, st[ct][2]);
        st[ct][3] = fmaf(rl4[ct].w, L2E, st[ct][3]);
      }
    }
    // ---- causal mask (diagonal tile only) ----
    if (kt == ktop) {
#pragma unroll
      for (int ct = 0; ct < 4; ++ct) {
        int kc0 = kb + ct * 16 + 4 * g;
#pragma unroll
        for (int j = 0; j < 4; ++j)
          if (kc0 + j > qrow) st[ct][j] = -1e30f;
      }
    }
    // ---- online softmax (exp2 domain): in-lane tree + 2 shfl; lane scalars ----
    float m0 = fmaxf(fmaxf(st[0][0], st[0][1]), fmaxf(st[0][2], st[0][3]));
#pragma unroll
    for (int ct = 1; ct < 4; ++ct)
      m0 = fmaxf(m0, fmaxf(fmaxf(st[ct][0], st[ct][1]), fmaxf(st[ct][2], st[ct][3])));
    m0 = fmaxf(m0, __shfl_xor(m0, 16));
    m0 = fmaxf(m0, __shfl_xor(m0, 32));
    float mn = fmaxf(mr, m0);
    float al = exp2f(mr - mn);
    mr = mn;
#pragma unroll
    for (int ct = 0; ct < 4; ++ct)
#pragma unroll
      for (int j = 0; j < 4; ++j) st[ct][j] = exp2f(st[ct][j] - mn);
    float rs = 0.f;
#pragma unroll
    for (int ct = 0; ct < 4; ++ct)
      rs += (st[ct][0] + st[ct][1]) + (st[ct][2] + st[ct][3]);
    rs += __shfl_xor(rs, 16);
    rs += __shfl_xor(rs, 32);
    lr = lr * al + rs;
#pragma unroll
    for (int ct = 0; ct < 4; ++ct) {
      ot[ct][0] *= al; ot[ct][1] *= al; ot[ct][2] *= al; ot[ct][3] *= al;
    }
    // ---- P -> LDS rows [q=cl][k]: 4x ds_write_b64 (wave-private, in-order) ----
#pragma unroll
    for (int ct = 0; ct < 4; ++ct) {
      us4 pk;
      pk[0] = cbf(st[ct][0]); pk[1] = cbf(st[ct][1]);
      pk[2] = cbf(st[ct][2]); pk[3] = cbf(st[ct][3]);
      *(us4*)(pw + cl * 72 + ct * 16 + g * 4) = pk;
    }
    // ---- PV SWAPPED: ot[ct] += mfma(V_frag, P_frag); P read = B-frag b128 ----
#pragma unroll
    for (int kk = 0; kk < 2; ++kk) {
      bf8 pf = __builtin_bit_cast(bf8, *(const us8*)(pw + cl * 72 + kk * 32 + g * 8));
#pragma unroll
      for (int ct = 0; ct < 4; ++ct)
        ot[ct] = __builtin_amdgcn_mfma_f32_16x16x32_bf16(vf[kk][ct], pf, ot[ct], 0, 0, 0);
    }
  }
  // ---- epilogue: O /= l; d = 16ct+4g+j -> chunk-swizzled us4 stores ----
  float inv = 1.0f / lr;
  const int s = qrow;
  unsigned short* aor = AO + (((size_t)b << 11) + s) * 512 + h * 64;
#pragma unroll
  for (int ct = 0; ct < 4; ++ct) {
    int chunk = 2 * ct + (g >> 1);
    int base = (4 * (g & 1)) | ((chunk ^ (s & 7)) << 3);
    us4 o;
    o[0] = cbf(ot[ct][0] * inv); o[1] = cbf(ot[ct][1] * inv);
    o[2] = cbf(ot[ct][2] * inv); o[3] = cbf(ot[ct][3] * inv);
    *(us4*)(aor + base) = o;
  }
}

// ------------------------------------ launch ------------------------------------
extern "C" void kernel_launch(void* const* d_in, const int* in_sizes, int n_in,
                              void* d_out, int out_size, void* d_ws, size_t ws_size,
                              hipStream_t stream) {
  const float* x    = (const float*)d_in[0];
  const float* Wqkv = (const float*)d_in[1];
  const float* bqkv = (const float*)d_in[2];
  const float* Wout = (const float*)d_in[3];
  const float* bout = (const float*)d_in[4];
  const float* rel  = (const float*)d_in[5];
  float* out = (float*)d_out;

  unsigned short* Qw  = (unsigned short*)d_ws;
  unsigned short* Kw  = Qw  + 8388608;
  unsigned short* Vw  = Kw  + 8388608;
  unsigned short* XA  = Vw  + 8388608;    // Xb (pre-attn) then AO (post-attn)
  unsigned short* WtQ = XA  + 8388608;
  unsigned short* WtO = WtQ + 786432;
  unsigned short* relt= WtO + 262144;
  const bool useT = ws_size >= (34603008ULL + 33554432ULL) * 2ULL;  // base + rel table

  k_convert_x<<<dim3(4096), dim3(256), 0, stream>>>(x, XA);
  k_transpose_w<<<dim3(16, 48), dim3(256), 0, stream>>>(Wqkv, WtQ, 1536);
  k_transpose_w<<<dim3(16, 16), dim3(256), 0, stream>>>(Wout, WtO, 512);
  if (useT) k_relconv<<<dim3(32768), dim3(256), 0, stream>>>(rel, relt);
  k_gemm<0><<<dim3(128, 12), dim3(256), 0, stream>>>(XA, WtQ, bqkv, nullptr, Qw, Kw, Vw);
  if (useT) k_attn<true ><<<dim3(2048), dim3(256), 0, stream>>>(Qw, Kw, Vw, rel, relt, XA);
  else      k_attn<false><<<dim3(2048), dim3(256), 0, stream>>>(Qw, Kw, Vw, rel, relt, XA);
  k_gemm<1><<<dim3(128, 4), dim3(256), 0, stream>>>(XA, WtO, bout, out, nullptr, nullptr, nullptr);
}

// Round 21
// 197.209 us; speedup vs baseline: 3.1786x; 1.0127x over previous
//
#include <hip/hip_runtime.h>
#include <cstdint>

// CausalSelfAttention fused pipeline, all-bf16 MFMA path.
// R21 = R20 (best: 199.7us; swapped-QK^T + exp2 softmax + 4-batch-wave grid)
// plus three measured-inefficiency fixes, structure frozen:
//  (1) P-LDS stride 64 + XOR-chunk swizzle (stride-72 caused the 3.24M bank
//      conflicts that appeared in R16; 68 broke b128 alignment).
//  (2) T13 defer-max: skip O/l rescale unless __any(m0 > mr + 8*log2e).
//  (3) relconv rewritten: one wave per (h,q16,kt) tile, coalesced 256B row
//      reads -> wave-private LDS -> transpose -> coalesced us4 writes.
// ws layout (ushort): Qf[8.39M] Kf[8.39M] Vf[8.39M] XbAO[8.39M] WtQ[786K] WtO[262K] [relt 33.55M]

#define DEVI __device__ __forceinline__

typedef __bf16 bf8 __attribute__((ext_vector_type(8)));
typedef float f4 __attribute__((ext_vector_type(4)));
typedef unsigned short us8 __attribute__((ext_vector_type(8)));
typedef unsigned short us4 __attribute__((ext_vector_type(4)));

typedef const unsigned int __attribute__((address_space(1))) gu32;
typedef unsigned int __attribute__((address_space(3))) lu32;

#define L2E 1.44269504088896f

DEVI unsigned short f2bf(float f) {  // RNE f32->bf16 (prep/GEMM epilogues)
  unsigned u = __builtin_bit_cast(unsigned, f);
  u += 0x7fffu + ((u >> 16) & 1u);
  return (unsigned short)(u >> 16);
}

DEVI unsigned short cbf(float f) {   // compiler-lowered cast (v_cvt_pk_bf16_f32 pairs)
  return __builtin_bit_cast(unsigned short, (__bf16)f);
}

DEVI void gl_lds16(const void* g, void* l) {
  __builtin_amdgcn_global_load_lds((gu32*)g, (lu32*)l, 16, 0, 0);
}

// ---------------- prep: x (f32 [16384][512]) -> bf16, chunk-swizzled ----------------
__global__ __launch_bounds__(256) void k_convert_x(const float* __restrict__ x,
                                                   unsigned short* __restrict__ xb) {
  int c = blockIdx.x * 256 + threadIdx.x;   // 1,048,576 chunks
  int row = c >> 6, cl = c & 63;
  const float* s = x + ((size_t)row << 9) + (cl << 3);
  float4 a = *(const float4*)s;
  float4 b = *(const float4*)(s + 4);
  us8 o;
  o[0]=f2bf(a.x); o[1]=f2bf(a.y); o[2]=f2bf(a.z); o[3]=f2bf(a.w);
  o[4]=f2bf(b.x); o[5]=f2bf(b.y); o[6]=f2bf(b.z); o[7]=f2bf(b.w);
  int p = (cl & ~7) | ((cl & 7) ^ (row & 7));
  *(us8*)(xb + ((size_t)row << 9) + (p << 3)) = o;
}

// ------------- prep: W [512][N] f32 -> Wt [N][512] bf16, chunk-swizzled -------------
__global__ __launch_bounds__(256) void k_transpose_w(const float* __restrict__ W,
                                                     unsigned short* __restrict__ Wt, int N) {
  __shared__ float t[32][33];
  int k0 = blockIdx.x * 32, n0 = blockIdx.y * 32;
  int tx = threadIdx.x & 31, ty = threadIdx.x >> 5;
#pragma unroll
  for (int r = 0; r < 4; ++r)
    t[ty + r * 8][tx] = W[(size_t)(k0 + ty + r * 8) * N + n0 + tx];
  __syncthreads();
#pragma unroll
  for (int r = 0; r < 4; ++r) {
    int n = n0 + ty + r * 8, k = k0 + tx;
    int k2 = (k & ~63) | ((((k >> 3) & 7) ^ (n & 7)) << 3) | (k & 7);
    Wt[((size_t)n << 9) + k2] = f2bf(t[tx][ty + r * 8]);
  }
}

// ---- prep: rel f32 [h][q][k] -> bf16 table, SWAPPED frag order, PRE-SCALED by log2e ----
// One WAVE per (h,q16,kt) tile: coalesced 16x(256B) row reads -> wave-private LDS
// -> transpose reads -> coalesced us4 writes. Output layout identical to R20:
// relt[h][q16][kt][ct][lane][j] = rel[q16*16+(lane&15)][kt*64+ct*16+4*(lane>>4)+j]*L2E
__global__ __launch_bounds__(256) void k_relconv(const float* __restrict__ rel,
                                                 unsigned short* __restrict__ relt) {
  __shared__ __align__(16) float tl[4][16][68];
  int wv = threadIdx.x >> 6, lane = threadIdx.x & 63;
  int t = blockIdx.x * 4 + wv;              // 32768 tiles
  int kt = t & 31, q16 = (t >> 5) & 127, h = t >> 12;
  if (kt > (q16 >> 2)) return;              // above-diagonal tiles never read
  // coalesced load: lanes 4r..4r+3 cover row r's 64 cols (4 x float4 each)
  const float* src = rel + ((size_t)h << 22) +
                     ((size_t)((q16 << 4) + (lane >> 2)) << 11) + (kt << 6) + (lane & 3) * 16;
  float4 v0 = *(const float4*)(src);
  float4 v1 = *(const float4*)(src + 4);
  float4 v2 = *(const float4*)(src + 8);
  float4 v3 = *(const float4*)(src + 12);
  float* dst = &tl[wv][lane >> 2][(lane & 3) * 16];
  *(float4*)(dst) = v0; *(float4*)(dst + 4) = v1;
  *(float4*)(dst + 8) = v2; *(float4*)(dst + 12) = v3;
  // same-wave LDS ordering: no barrier needed
  size_t tb = (((((size_t)h << 7) | q16) << 5) | kt) << 2;
#pragma unroll
  for (int ct = 0; ct < 4; ++ct) {
    const float* rp = &tl[wv][lane & 15][ct * 16 + ((lane >> 4) << 2)];
    float4 rv = *(const float4*)rp;
    us4 o;
    o[0] = f2bf(rv.x * L2E); o[1] = f2bf(rv.y * L2E);
    o[2] = f2bf(rv.z * L2E); o[3] = f2bf(rv.w * L2E);
    *(us4*)(relt + (((tb | ct) << 6) | lane) * 4) = o;
  }
}

// ---------------- GEMM: C[M][col] = A[M][512] * Bt[col][512]^T + bias ----------------
template <int EPI>
__global__ __launch_bounds__(256, 2)
void k_gemm(const unsigned short* __restrict__ Ag, const unsigned short* __restrict__ Bg,
            const float* __restrict__ bias, float* __restrict__ Of,
            unsigned short* __restrict__ Oq, unsigned short* __restrict__ Ok,
            unsigned short* __restrict__ Ov) {
  __shared__ __align__(16) unsigned short lds[128 * 64 * 2];
  unsigned short* Al = lds;
  unsigned short* Bl = lds + 128 * 64;
  const int tid = threadIdx.x, wv = tid >> 6, lane = tid & 63, g = lane >> 4, cl = lane & 15;
  const int wm = wv >> 1, wn = wv & 1;
  const int row0 = blockIdx.x * 128, col0 = blockIdx.y * 128;
  f4 acc[4][4];
#pragma unroll
  for (int i = 0; i < 4; ++i)
#pragma unroll
    for (int j = 0; j < 4; ++j) acc[i][j] = (f4){0.f, 0.f, 0.f, 0.f};

  for (int kt = 0; kt < 8; ++kt) {
#pragma unroll
    for (int j = 0; j < 4; ++j) {
      int ci = wv * 4 + j;
      int gci = ci * 64 + lane;
      int r = gci >> 3, cc = gci & 7;
      gl_lds16(Ag + ((size_t)(row0 + r) << 9) + kt * 64 + cc * 8, Al + ci * 512);
      gl_lds16(Bg + ((size_t)(col0 + r) << 9) + kt * 64 + cc * 8, Bl + ci * 512);
    }
    __syncthreads();
#pragma unroll
    for (int kk = 0; kk < 2; ++kk) {
      bf8 af[4], bb[4];
#pragma unroll
      for (int mf = 0; mf < 4; ++mf) {
        int r = wm * 64 + mf * 16 + cl;
        int cc = (kk * 4 + g) ^ (r & 7);
        af[mf] = *(const bf8*)(Al + r * 64 + cc * 8);
      }
#pragma unroll
      for (int nf = 0; nf < 4; ++nf) {
        int r = wn * 64 + nf * 16 + cl;
        int cc = (kk * 4 + g) ^ (r & 7);
        bb[nf] = *(const bf8*)(Bl + r * 64 + cc * 8);
      }
#pragma unroll
      for (int mf = 0; mf < 4; ++mf)
#pragma unroll
        for (int nf = 0; nf < 4; ++nf)
          acc[mf][nf] = __builtin_amdgcn_mfma_f32_16x16x32_bf16(af[mf], bb[nf], acc[mf][nf], 0, 0, 0);
    }
    __syncthreads();
  }

  if (EPI == 1) {
#pragma unroll
    for (int nf = 0; nf < 4; ++nf) {
      int col = col0 + wn * 64 + nf * 16 + cl;
      float bv = bias[col];
#pragma unroll
      for (int mf = 0; mf < 4; ++mf) {
#pragma unroll
        for (int j = 0; j < 4; ++j) {
          int row = row0 + wm * 64 + mf * 16 + 4 * g + j;  // C/D: col=lane&15, row=4*(lane>>4)+reg
          Of[((size_t)row << 9) + col] = acc[mf][nf][j] + bv;
        }
      }
    }
  } else {
    const int which = col0 >> 9;   // block-uniform
#pragma unroll
    for (int nf = 0; nf < 4; ++nf) {
      int col = col0 + wn * 64 + nf * 16 + cl;
      float bv = bias[col];
      int d = col & 63, h = (col >> 6) & 7;
#pragma unroll
      for (int mf = 0; mf < 4; ++mf) {
        int row = row0 + wm * 64 + mf * 16 + 4 * g;   // j = 0 row
        int b = row >> 11, s = row & 2047;
        size_t fb = ((size_t)b * 8 + h) * 131072;     // per-(b,h) fragment array
        if (which == 0) {
          // Q frag: [q16][kk][lane][8]; scale folds softmax 1/8 AND log2(e)
#pragma unroll
          for (int j = 0; j < 4; ++j) {
            int ss = s + j;
            size_t off = fb + (size_t)((ss >> 4) * 1024 + (d >> 5) * 512 +
                                       (((d >> 3) & 3) * 16 + (ss & 15)) * 8 + (d & 7));
            Oq[off] = f2bf((acc[mf][nf][j] + bv) * (0.125f * L2E));
          }
        } else if (which == 1) {
          // K frag: [kt][kk][ct][lane][8]
#pragma unroll
          for (int j = 0; j < 4; ++j) {
            int ss = s + j;
            size_t off = fb + (size_t)((ss >> 6) * 4096 + (d >> 5) * 2048 + ((ss >> 4) & 3) * 512 +
                                       (((d >> 3) & 3) * 16 + (ss & 15)) * 8 + (d & 7));
            Ok[off] = f2bf(acc[mf][nf][j] + bv);
          }
        } else {
          // V frag: [kt][kk][ct][lane][8]
          us4 o;
#pragma unroll
          for (int j = 0; j < 4; ++j) o[j] = f2bf(acc[mf][nf][j] + bv);
          size_t off = fb + (size_t)((s >> 6) * 4096 + ((s >> 5) & 1) * 2048 + (d >> 4) * 512 +
                                     ((((s >> 3) & 3) * 16) + (d & 15)) * 8 + (s & 7));
          *(us4*)(Ov + off) = o;
        }
      }
    }
  }
}

// ------------------------------- flash attention --------------------------------
// block = 4 waves = 4 BATCHES of the same (h, q16) slab; 2048 blocks big-first.
// SWAPPED tile body (lane owns q-row), exp2 softmax with T13 defer-max,
// P via XOR-chunk-swizzled LDS rows (stride 64, conflict-free, 16B aligned).
template <bool RELT>
__global__ __launch_bounds__(256, 4)
void k_attn(const unsigned short* __restrict__ Qf, const unsigned short* __restrict__ Kf,
            const unsigned short* __restrict__ Vf, const float* __restrict__ rel,
            const unsigned short* __restrict__ relt, unsigned short* __restrict__ AO) {
  __shared__ __align__(16) unsigned short Pl[4][16 * 64];
  const int tid = threadIdx.x, wv = tid >> 6, lane = tid & 63, g = lane >> 4, cl = lane & 15;
  int bid = blockIdx.x;                        // 2048 blocks
  int h = bid & 7;                             // head's relt panel pinned to one XCD
  int rest = bid >> 3;                         // 0..255
  int q16 = 127 - (rest >> 1);                 // 127..0, big-first
  int b = ((rest & 1) << 2) | wv;              // 0..7
  const int rX = q16 << 4;
  const int ktop = q16 >> 2;                   // diagonal k-tile index
  const int qrow = rX + cl;                    // this lane's q-row (swapped layout)
  size_t fb = (((size_t)b << 3) + h) * 131072;
  const unsigned short* Qp = Qf + fb;
  const unsigned short* Kp = Kf + fb;
  const unsigned short* Vp = Vf + fb;
  const float* relp = rel + ((size_t)h << 22);
  unsigned short* pw = Pl[wv];

  bf8 qf[2];
#pragma unroll
  for (int kk = 0; kk < 2; ++kk)
    qf[kk] = *(const bf8*)(Qp + q16 * 1024 + kk * 512 + lane * 8);

  f4 ot[4];                                    // O^T frags: ot[ct][j] = O[q=cl][d=16ct+4g+j]
  float mr = -1e30f, lr = 0.f;
#pragma unroll
  for (int ct = 0; ct < 4; ++ct) ot[ct] = (f4){0.f, 0.f, 0.f, 0.f};

  for (int kt = 0; kt <= ktop; ++kt) {
    const int kb = kt << 6;
    const unsigned short* Kt = Kp + kt * 4096;
    const unsigned short* Vt = Vp + kt * 4096;
    // ---- ALL loads up front: K (QK^T dep), then V, then rel (FIFO vmcnt) ----
    bf8 kf[2][4], vf[2][4];
#pragma unroll
    for (int kk = 0; kk < 2; ++kk)
#pragma unroll
      for (int ct = 0; ct < 4; ++ct)
        kf[kk][ct] = *(const bf8*)(Kt + kk * 2048 + ct * 512 + lane * 8);
#pragma unroll
    for (int kk = 0; kk < 2; ++kk)
#pragma unroll
      for (int ct = 0; ct < 4; ++ct)
        vf[kk][ct] = *(const bf8*)(Vt + kk * 2048 + ct * 512 + lane * 8);
    us4 rt4[4];
    float4 rl4[4];
    if constexpr (RELT) {
      const unsigned short* tb = relt + (((((size_t)h << 7) | q16) << 5) | kt) * 1024;
#pragma unroll
      for (int ct = 0; ct < 4; ++ct)
        rt4[ct] = *(const us4*)(tb + ((ct << 6) | lane) * 4);
    } else {
#pragma unroll
      for (int ct = 0; ct < 4; ++ct)
        rl4[ct] = *(const float4*)(relp + ((size_t)qrow << 11) + kb + ct * 16 + g * 4);
    }
    // ---- QK^T SWAPPED: st[ct][j] = S[q=cl][k = kb + 16ct + 4g + j] ----
    f4 st[4];
#pragma unroll
    for (int ct = 0; ct < 4; ++ct) st[ct] = (f4){0.f, 0.f, 0.f, 0.f};
#pragma unroll
    for (int kk = 0; kk < 2; ++kk)
#pragma unroll
      for (int ct = 0; ct < 4; ++ct)
        st[ct] = __builtin_amdgcn_mfma_f32_16x16x32_bf16(kf[kk][ct], qf[kk], st[ct], 0, 0, 0);
    // ---- rel_pos add (already in log2e domain) ----
    if constexpr (RELT) {
#pragma unroll
      for (int ct = 0; ct < 4; ++ct)
#pragma unroll
        for (int j = 0; j < 4; ++j)
          st[ct][j] += __builtin_bit_cast(float, (unsigned)rt4[ct][j] << 16);
    } else {
#pragma unroll
      for (int ct = 0; ct < 4; ++ct) {
        st[ct][0] = fmaf(rl4[ct].x, L2E, st[ct][0]);
        st[ct][1] = fmaf(rl4[ct].y, L2E, st[ct][1]);
        st[ct][2] = fmaf(rl4[ct].z, L2E, st[ct][2]);
        st[ct][3] = fmaf(rl4[ct].w, L2E, st[ct][3]);
      }
    }
    // ---- causal mask (diagonal tile only) ----
    if (kt == ktop) {
#pragma unroll
      for (int ct = 0; ct < 4; ++ct) {
        int kc0 = kb + ct * 16 + 4 * g;
#pragma unroll
        for (int j = 0; j < 4; ++j)
          if (kc0 + j > qrow) st[ct][j] = -1e30f;
      }
    }
    // ---- online softmax (exp2 domain) with T13 defer-max ----
    float m0 = fmaxf(fmaxf(st[0][0], st[0][1]), fmaxf(st[0][2], st[0][3]));
#pragma unroll
    for (int ct = 1; ct < 4; ++ct)
      m0 = fmaxf(m0, fmaxf(fmaxf(st[ct][0], st[ct][1]), fmaxf(st[ct][2], st[ct][3])));
    m0 = fmaxf(m0, __shfl_xor(m0, 16));
    m0 = fmaxf(m0, __shfl_xor(m0, 32));
    if (__any(m0 > mr + 11.54f)) {             // THR = 8*log2(e): P bounded by 2^11.54
      float mn = fmaxf(mr, m0);
      float al = exp2f(mr - mn);
      mr = mn;
      lr *= al;
#pragma unroll
      for (int ct = 0; ct < 4; ++ct) {
        ot[ct][0] *= al; ot[ct][1] *= al; ot[ct][2] *= al; ot[ct][3] *= al;
      }
    }
#pragma unroll
    for (int ct = 0; ct < 4; ++ct)
#pragma unroll
      for (int j = 0; j < 4; ++j) st[ct][j] = exp2f(st[ct][j] - mr);
    float rs = 0.f;
#pragma unroll
    for (int ct = 0; ct < 4; ++ct)
      rs += (st[ct][0] + st[ct][1]) + (st[ct][2] + st[ct][3]);
    rs += __shfl_xor(rs, 16);
    rs += __shfl_xor(rs, 32);
    lr += rs;
    // ---- P -> LDS rows [q=cl], XOR-chunk swizzled (stride 64, conflict-free) ----
    // write: k=16ct+4g+j -> chunk 2ct+(g>>1), offset 4(g&1); swz chunk ^= (cl&7)
#pragma unroll
    for (int ct = 0; ct < 4; ++ct) {
      us4 pk;
      pk[0] = cbf(st[ct][0]); pk[1] = cbf(st[ct][1]);
      pk[2] = cbf(st[ct][2]); pk[3] = cbf(st[ct][3]);
      *(us4*)(pw + cl * 64 + (((2 * ct + (g >> 1)) ^ (cl & 7)) << 3) + ((g & 1) << 2)) = pk;
    }
    // ---- PV SWAPPED: read chunk 4kk+g (swz ^(cl&7)) as B-frag b128 ----
#pragma unroll
    for (int kk = 0; kk < 2; ++kk) {
      bf8 pf = __builtin_bit_cast(bf8,
                 *(const us8*)(pw + cl * 64 + (((4 * kk + g) ^ (cl & 7)) << 3)));
#pragma unroll
      for (int ct = 0; ct < 4; ++ct)
        ot[ct] = __builtin_amdgcn_mfma_f32_16x16x32_bf16(vf[kk][ct], pf, ot[ct], 0, 0, 0);
    }
  }
  // ---- epilogue: O /= l; d = 16ct+4g+j -> chunk-swizzled us4 stores ----
  float inv = 1.0f / lr;
  const int s = qrow;
  unsigned short* aor = AO + (((size_t)b << 11) + s) * 512 + h * 64;
#pragma unroll
  for (int ct = 0; ct < 4; ++ct) {
    int chunk = 2 * ct + (g >> 1);
    int base = (4 * (g & 1)) | ((chunk ^ (s & 7)) << 3);
    us4 o;
    o[0] = cbf(ot[ct][0] * inv); o[1] = cbf(ot[ct][1] * inv);
    o[2] = cbf(ot[ct][2] * inv); o[3] = cbf(ot[ct][3] * inv);
    *(us4*)(aor + base) = o;
  }
}

// ------------------------------------ launch ------------------------------------
extern "C" void kernel_launch(void* const* d_in, const int* in_sizes, int n_in,
                              void* d_out, int out_size, void* d_ws, size_t ws_size,
                              hipStream_t stream) {
  const float* x    = (const float*)d_in[0];
  const float* Wqkv = (const float*)d_in[1];
  const float* bqkv = (const float*)d_in[2];
  const float* Wout = (const float*)d_in[3];
  const float* bout = (const float*)d_in[4];
  const float* rel  = (const float*)d_in[5];
  float* out = (float*)d_out;

  unsigned short* Qw  = (unsigned short*)d_ws;
  unsigned short* Kw  = Qw  + 8388608;
  unsigned short* Vw  = Kw  + 8388608;
  unsigned short* XA  = Vw  + 8388608;    // Xb (pre-attn) then AO (post-attn)
  unsigned short* WtQ = XA  + 8388608;
  unsigned short* WtO = WtQ + 786432;
  unsigned short* relt= WtO + 262144;
  const bool useT = ws_size >= (34603008ULL + 33554432ULL) * 2ULL;  // base + rel table

  k_convert_x<<<dim3(4096), dim3(256), 0, stream>>>(x, XA);
  k_transpose_w<<<dim3(16, 48), dim3(256), 0, stream>>>(Wqkv, WtQ, 1536);
  k_transpose_w<<<dim3(16, 16), dim3(256), 0, stream>>>(Wout, WtO, 512);
  if (useT) k_relconv<<<dim3(8192), dim3(256), 0, stream>>>(rel, relt);
  k_gemm<0><<<dim3(128, 12), dim3(256), 0, stream>>>(XA, WtQ, bqkv, nullptr, Qw, Kw, Vw);
  if (useT) k_attn<true ><<<dim3(2048), dim3(256), 0, stream>>>(Qw, Kw, Vw, rel, relt, XA);
  else      k_attn<false><<<dim3(2048), dim3(256), 0, stream>>>(Qw, Kw, Vw, rel, relt, XA);
  k_gemm<1><<<dim3(128, 4), dim3(256), 0, stream>>>(XA, WtO, bout, out, nullptr, nullptr, nullptr);
}